// Round 1
// baseline (157.088 us; speedup 1.0000x reference)
//
#include <hip/hip_runtime.h>
#include <cstdint>
#include <cstddef>

#define CCH   512
#define FSCOPE 27
#define HWSP  3136
#define NBATCH 16
#define NCOL  (NBATCH*HWSP)   // 50176

#define BM 128
#define BN 128
#define BK 64
#define NKT (CCH/BK)          // 8

#define PI_F 3.14159265358979323846f

typedef __bf16 bf16x8 __attribute__((ext_vector_type(8)));
typedef float  f32x4  __attribute__((ext_vector_type(4)));

static __device__ __forceinline__ unsigned short f2bf(float f) {
  unsigned u = __builtin_bit_cast(unsigned, f);
  unsigned r = 0x7FFFu + ((u >> 16) & 1u);
  return (unsigned short)((u + r) >> 16);
}

// ---- kernel 1: fk[m] = FFT(delta - k_rolled)[m], 27-tap filter at offsets j-13
__global__ void k_fk(const float* __restrict__ w, float* __restrict__ fk) {
  int m = threadIdx.x;
  float re = 1.0f, im = 0.0f;
  for (int j = 0; j < FSCOPE; ++j) {
    int t = (m * (j - FSCOPE/2)) % CCH;
    if (t < 0) t += CCH;
    float ang = (2.0f * PI_F / CCH) * (float)t;
    float s, c;
    sincosf(ang, &s, &c);
    float wj = w[j];
    re -= wj * c;   // e^{-i theta} = cos - i sin
    im += wj * s;
  }
  fk[2*m]   = re;
  fk[2*m+1] = im;
}

// ---- kernel 2: h[d] = (1/512) sum_m Re( e^{+i 2pi m d/512} / fk[m] )
__global__ void k_h(const float* __restrict__ fk, float* __restrict__ h) {
  int d = threadIdx.x;
  double acc = 0.0;
  for (int m = 0; m < CCH; ++m) {
    int t = (m * d) & (CCH - 1);
    float ang = (2.0f * PI_F / CCH) * (float)t;
    float s, c;
    sincosf(ang, &s, &c);
    float re = fk[2*m], im = fk[2*m+1];
    float inv = 1.0f / (re*re + im*im);
    acc += (double)((c*re + s*im) * inv);
  }
  h[d] = (float)(acc / (double)CCH);
}

// ---- kernel 3: H[m][k] = bf16( h[(m-k) mod 512] ), row-major 512x512
__global__ void k_buildH(const float* __restrict__ h, unsigned short* __restrict__ Hm) {
  int m = blockIdx.x;
  for (int k = threadIdx.x; k < CCH; k += blockDim.x) {
    Hm[m*CCH + k] = f2bf(h[(m - k) & (CCH - 1)]);
  }
}

// ---- kernel 4: Y = H * X   (batched over n via flattened columns)
// grid = 4 m-tiles * 392 col-tiles = 1568 blocks, 256 threads (4 waves)
__global__ __launch_bounds__(256, 2)
void k_gemm(const float* __restrict__ X, const unsigned short* __restrict__ Hm,
            float* __restrict__ Y) {
  __shared__ __align__(16) unsigned char lds[BM*BK*2 + BN*BK*2]; // 16KB A + 16KB B

  const int tid  = threadIdx.x;
  const int lane = tid & 63;
  const int w    = tid >> 6;

  // XCD-aware swizzle (1568 = 8 * 196, exact)
  int bid = blockIdx.x;
  int cpx = gridDim.x >> 3;
  int swz = (bid & 7) * cpx + (bid >> 3);
  const int tm = swz & 3;       // m-tile fastest -> same col-tile adjacent in XCD
  const int tc = swz >> 2;

  const int m0 = tm * BM;
  const int j0 = tc * BN;

  unsigned char* Al = lds;
  unsigned char* Bl = lds + BM*BK*2;

  // B staging mapping: thread -> 4 cols (float4) x 8 k's
  const int fg = tid & 31;       // cols 4*fg .. 4*fg+3
  const int kg = tid >> 5;       // k sub-block of 8 within BK
  const int jb = j0 + fg*4;
  const int nb = jb / HWSP;      // float4 never crosses batch (3136 % 4 == 0)
  const int sb = jb - nb * HWSP;
  const float* Xb = X + (size_t)nb * (CCH*(size_t)HWSP) + sb;

  f32x4 acc[4][4];
  #pragma unroll
  for (int i = 0; i < 4; ++i)
    #pragma unroll
    for (int j = 0; j < 4; ++j)
      acc[i][j] = (f32x4){0.f, 0.f, 0.f, 0.f};

  const int wr = w >> 1, wc = w & 1;   // wave -> 64x64 quadrant

  for (int kt = 0; kt < NKT; ++kt) {
    // B global loads (regs only, safe before barrier)
    float4 bv[8];
    const float* Xk = Xb + (size_t)(kt*BK + kg*8) * HWSP;
    #pragma unroll
    for (int kk = 0; kk < 8; ++kk)
      bv[kk] = *reinterpret_cast<const float4*>(Xk + (size_t)kk * HWSP);

    if (kt > 0) __syncthreads();   // previous tile fully consumed

    // A: global_load_lds, pre-swizzled source, linear LDS dest (rule #21 / m173)
    #pragma unroll
    for (int i = 0; i < 4; ++i) {
      int m0w = w*32 + i*8;                 // wave-uniform
      int m   = m0w + (lane >> 3);
      int c   = lane & 7;
      const unsigned short* src =
          Hm + (size_t)(m0 + m) * CCH + kt*BK + 8*(c ^ (m & 7));
      unsigned char* dst = Al + m0w * 128;  // + lane*16 by HW
      __builtin_amdgcn_global_load_lds(
          (const __attribute__((address_space(1))) void*)src,
          (__attribute__((address_space(3))) void*)dst, 16, 0, 0);
    }

    // B: cvt fp32->bf16, transpose in regs, swizzled ds_write_b128
    #pragma unroll
    for (int c = 0; c < 4; ++c) {
      unsigned short b[8];
      #pragma unroll
      for (int kk = 0; kk < 8; ++kk) {
        float f = (c==0) ? bv[kk].x : (c==1) ? bv[kk].y : (c==2) ? bv[kk].z : bv[kk].w;
        b[kk] = f2bf(f);
      }
      int col = fg*4 + c;
      int4 v;
      v.x = (int)b[0] | ((int)b[1] << 16);
      v.y = (int)b[2] | ((int)b[3] << 16);
      v.z = (int)b[4] | ((int)b[5] << 16);
      v.w = (int)b[6] | ((int)b[7] << 16);
      *reinterpret_cast<int4*>(Bl + col*128 + ((kg*16) ^ ((col & 7) << 4))) = v;
    }

    __syncthreads();   // A gload_lds drained + B writes visible

    #pragma unroll
    for (int ks = 0; ks < 2; ++ks) {
      const int kbyte = ks*64 + ((lane >> 4) << 4);
      bf16x8 af[4], bfr[4];
      #pragma unroll
      for (int fm = 0; fm < 4; ++fm) {
        int m = wr*64 + fm*16 + (lane & 15);
        af[fm] = *reinterpret_cast<const bf16x8*>(Al + m*128 + (kbyte ^ ((m & 7) << 4)));
      }
      #pragma unroll
      for (int fn = 0; fn < 4; ++fn) {
        int col = wc*64 + fn*16 + (lane & 15);
        bfr[fn] = *reinterpret_cast<const bf16x8*>(Bl + col*128 + (kbyte ^ ((col & 7) << 4)));
      }
      #pragma unroll
      for (int fm = 0; fm < 4; ++fm)
        #pragma unroll
        for (int fn = 0; fn < 4; ++fn)
          acc[fm][fn] = __builtin_amdgcn_mfma_f32_16x16x32_bf16(
              af[fm], bfr[fn], acc[fm][fn], 0, 0, 0);
    }
  }

  // epilogue: C/D layout col = lane&15, row = (lane>>4)*4 + r  (m89/m91)
  #pragma unroll
  for (int fn = 0; fn < 4; ++fn) {
    int colg = j0 + wc*64 + fn*16 + (lane & 15);
    int n = colg / HWSP;
    int s = colg - n * HWSP;
    float* Yb = Y + (size_t)n * (CCH*(size_t)HWSP) + s;
    #pragma unroll
    for (int fm = 0; fm < 4; ++fm) {
      int mrow = m0 + wr*64 + fm*16 + ((lane >> 4) << 2);
      #pragma unroll
      for (int r = 0; r < 4; ++r)
        Yb[(size_t)(mrow + r) * HWSP] = acc[fm][fn][r];
    }
  }
}

extern "C" void kernel_launch(void* const* d_in, const int* in_sizes, int n_in,
                              void* d_out, int out_size, void* d_ws, size_t ws_size,
                              hipStream_t stream) {
  const float* X = (const float*)d_in[0];   // [16,512,56,56] f32
  const float* w = (const float*)d_in[1];   // [27] f32
  float* Y = (float*)d_out;

  float* fk          = (float*)d_ws;                                // 4 KB
  float* h           = (float*)((char*)d_ws + 4096);                // 2 KB
  unsigned short* Hm = (unsigned short*)((char*)d_ws + 8192);       // 512 KB

  k_fk    <<<1,   512, 0, stream>>>(w, fk);
  k_h     <<<1,   512, 0, stream>>>(fk, h);
  k_buildH<<<CCH, 256, 0, stream>>>(h, Hm);

  const int nblk = (CCH/BM) * (NCOL/BN);    // 4 * 392 = 1568
  k_gemm  <<<nblk, 256, 0, stream>>>(X, Hm, Y);
}

// Round 2
// 65.484 us; speedup vs baseline: 2.3989x; 2.3989x over previous
//
#include <hip/hip_runtime.h>
#include <cstdint>
#include <cstddef>

#define CCH   512
#define FSCOPE 27
#define HWSP  3136
#define NBATCH 16
#define NCOL  (NBATCH*HWSP)   // 50176

#define BM 128
#define BN 128
#define BK 64
#define NKT (CCH/BK)          // 8

#define PI_F 3.14159265358979323846f

typedef __bf16 bf16x8 __attribute__((ext_vector_type(8)));
typedef float  f32x4  __attribute__((ext_vector_type(4)));

static __device__ __forceinline__ unsigned short f2bf(float f) {
  unsigned u = __builtin_bit_cast(unsigned, f);
  unsigned r = 0x7FFFu + ((u >> 16) & 1u);
  return (unsigned short)((u + r) >> 16);
}

// ---- kernel 1 (fused fk + inverse DFT, parallel over d):
// block d, thread m: recompute fk[m] from the 27-tap filter, then the
// m-th term of h[d] = (1/512) sum_m Re( e^{+i 2pi m d/512} / fk[m] ).
__global__ __launch_bounds__(512)
void k_h2(const float* __restrict__ w, float* __restrict__ h) {
  __shared__ float red[8];
  const int d = blockIdx.x;
  const int m = threadIdx.x;

  // fk[m] = 1 - sum_j w[j] e^{-i 2pi m (j-13)/512}
  float re = 1.0f, im = 0.0f;
  #pragma unroll
  for (int j = 0; j < FSCOPE; ++j) {
    int t = (m * (j - FSCOPE/2)) % CCH;
    if (t < 0) t += CCH;
    float ang = (2.0f * PI_F / CCH) * (float)t;
    float s, c;
    sincosf(ang, &s, &c);
    float wj = w[j];
    re -= wj * c;
    im += wj * s;
  }

  int t = (m * d) & (CCH - 1);
  float ang = (2.0f * PI_F / CCH) * (float)t;
  float s, c;
  sincosf(ang, &s, &c);
  float inv = 1.0f / (re * re + im * im);
  float term = (c * re + s * im) * inv;

  // wave64 butterfly reduce
  #pragma unroll
  for (int off = 32; off > 0; off >>= 1)
    term += __shfl_down(term, off, 64);

  const int lane = m & 63, wv = m >> 6;
  if (lane == 0) red[wv] = term;
  __syncthreads();
  if (m == 0) {
    float tot = 0.f;
    #pragma unroll
    for (int i = 0; i < 8; ++i) tot += red[i];
    h[d] = tot / (float)CCH;
  }
}

// ---- kernel 2: H[m][k] = bf16( h[(m-k) mod 512] ), row-major 512x512
__global__ void k_buildH(const float* __restrict__ h, unsigned short* __restrict__ Hm) {
  int m = blockIdx.x;
  for (int k = threadIdx.x; k < CCH; k += blockDim.x) {
    Hm[m*CCH + k] = f2bf(h[(m - k) & (CCH - 1)]);
  }
}

// ---- kernel 3: Y = H * X   (batched over n via flattened columns)
// grid = 4 m-tiles * 392 col-tiles = 1568 blocks, 256 threads (4 waves)
__global__ __launch_bounds__(256, 2)
void k_gemm(const float* __restrict__ X, const unsigned short* __restrict__ Hm,
            float* __restrict__ Y) {
  __shared__ __align__(16) unsigned char lds[BM*BK*2 + BN*BK*2]; // 16KB A + 16KB B

  const int tid  = threadIdx.x;
  const int lane = tid & 63;
  const int w    = tid >> 6;

  // XCD-aware swizzle (1568 = 8 * 196, exact)
  int bid = blockIdx.x;
  int cpx = gridDim.x >> 3;
  int swz = (bid & 7) * cpx + (bid >> 3);
  const int tm = swz & 3;       // m-tile fastest -> same col-tile adjacent in XCD
  const int tc = swz >> 2;

  const int m0 = tm * BM;
  const int j0 = tc * BN;

  unsigned char* Al = lds;
  unsigned char* Bl = lds + BM*BK*2;

  // B staging mapping: thread -> 4 cols (float4) x 8 k's
  const int fg = tid & 31;       // cols 4*fg .. 4*fg+3
  const int kg = tid >> 5;       // k sub-block of 8 within BK
  const int jb = j0 + fg*4;
  const int nb = jb / HWSP;      // float4 never crosses batch (3136 % 4 == 0)
  const int sb = jb - nb * HWSP;
  const float* Xb = X + (size_t)nb * (CCH*(size_t)HWSP) + sb;

  f32x4 acc[4][4];
  #pragma unroll
  for (int i = 0; i < 4; ++i)
    #pragma unroll
    for (int j = 0; j < 4; ++j)
      acc[i][j] = (f32x4){0.f, 0.f, 0.f, 0.f};

  const int wr = w >> 1, wc = w & 1;   // wave -> 64x64 quadrant

  for (int kt = 0; kt < NKT; ++kt) {
    // B global loads (regs only, safe before barrier)
    float4 bv[8];
    const float* Xk = Xb + (size_t)(kt*BK + kg*8) * HWSP;
    #pragma unroll
    for (int kk = 0; kk < 8; ++kk)
      bv[kk] = *reinterpret_cast<const float4*>(Xk + (size_t)kk * HWSP);

    if (kt > 0) __syncthreads();   // previous tile fully consumed

    // A: global_load_lds, pre-swizzled source, linear LDS dest (rule #21 / m173)
    #pragma unroll
    for (int i = 0; i < 4; ++i) {
      int m0w = w*32 + i*8;                 // wave-uniform
      int m   = m0w + (lane >> 3);
      int c   = lane & 7;
      const unsigned short* src =
          Hm + (size_t)(m0 + m) * CCH + kt*BK + 8*(c ^ (m & 7));
      unsigned char* dst = Al + m0w * 128;  // + lane*16 by HW
      __builtin_amdgcn_global_load_lds(
          (const __attribute__((address_space(1))) void*)src,
          (__attribute__((address_space(3))) void*)dst, 16, 0, 0);
    }

    // B: cvt fp32->bf16, transpose in regs, swizzled ds_write_b128
    #pragma unroll
    for (int c = 0; c < 4; ++c) {
      unsigned short b[8];
      #pragma unroll
      for (int kk = 0; kk < 8; ++kk) {
        float f = (c==0) ? bv[kk].x : (c==1) ? bv[kk].y : (c==2) ? bv[kk].z : bv[kk].w;
        b[kk] = f2bf(f);
      }
      int col = fg*4 + c;
      int4 v;
      v.x = (int)b[0] | ((int)b[1] << 16);
      v.y = (int)b[2] | ((int)b[3] << 16);
      v.z = (int)b[4] | ((int)b[5] << 16);
      v.w = (int)b[6] | ((int)b[7] << 16);
      *reinterpret_cast<int4*>(Bl + col*128 + ((kg*16) ^ ((col & 7) << 4))) = v;
    }

    __syncthreads();   // A gload_lds drained + B writes visible

    #pragma unroll
    for (int ks = 0; ks < 2; ++ks) {
      const int kbyte = ks*64 + ((lane >> 4) << 4);
      bf16x8 af[4], bfr[4];
      #pragma unroll
      for (int fm = 0; fm < 4; ++fm) {
        int m = wr*64 + fm*16 + (lane & 15);
        af[fm] = *reinterpret_cast<const bf16x8*>(Al + m*128 + (kbyte ^ ((m & 7) << 4)));
      }
      #pragma unroll
      for (int fn = 0; fn < 4; ++fn) {
        int col = wc*64 + fn*16 + (lane & 15);
        bfr[fn] = *reinterpret_cast<const bf16x8*>(Bl + col*128 + (kbyte ^ ((col & 7) << 4)));
      }
      #pragma unroll
      for (int fm = 0; fm < 4; ++fm)
        #pragma unroll
        for (int fn = 0; fn < 4; ++fn)
          acc[fm][fn] = __builtin_amdgcn_mfma_f32_16x16x32_bf16(
              af[fm], bfr[fn], acc[fm][fn], 0, 0, 0);
    }
  }

  // epilogue: C/D layout col = lane&15, row = (lane>>4)*4 + r  (m89/m91)
  #pragma unroll
  for (int fn = 0; fn < 4; ++fn) {
    int colg = j0 + wc*64 + fn*16 + (lane & 15);
    int n = colg / HWSP;
    int s = colg - n * HWSP;
    float* Yb = Y + (size_t)n * (CCH*(size_t)HWSP) + s;
    #pragma unroll
    for (int fm = 0; fm < 4; ++fm) {
      int mrow = m0 + wr*64 + fm*16 + ((lane >> 4) << 2);
      #pragma unroll
      for (int r = 0; r < 4; ++r)
        Yb[(size_t)(mrow + r) * HWSP] = acc[fm][fn][r];
    }
  }
}

extern "C" void kernel_launch(void* const* d_in, const int* in_sizes, int n_in,
                              void* d_out, int out_size, void* d_ws, size_t ws_size,
                              hipStream_t stream) {
  const float* X = (const float*)d_in[0];   // [16,512,56,56] f32
  const float* w = (const float*)d_in[1];   // [27] f32
  float* Y = (float*)d_out;

  float* h           = (float*)d_ws;                                // 2 KB
  unsigned short* Hm = (unsigned short*)((char*)d_ws + 4096);       // 512 KB

  k_h2    <<<CCH, 512, 0, stream>>>(w, h);
  k_buildH<<<CCH, 256, 0, stream>>>(h, Hm);

  const int nblk = (CCH/BM) * (NCOL/BN);    // 4 * 392 = 1568
  k_gemm  <<<nblk, 256, 0, stream>>>(X, Hm, Y);
}

// Round 3
// 65.312 us; speedup vs baseline: 2.4052x; 1.0026x over previous
//
#include <hip/hip_runtime.h>
#include <cstdint>
#include <cstddef>

#define CCH   512
#define FSCOPE 27
#define HWSP  3136
#define NBATCH 16
#define NCOL  (NBATCH*HWSP)   // 50176

#define BM 128
#define BN 128
#define BK 64
#define NKT (CCH/BK)          // 8

#define PI_F 3.14159265358979323846f

typedef __bf16 bf16x8 __attribute__((ext_vector_type(8)));
typedef float  f32x4  __attribute__((ext_vector_type(4)));

static __device__ __forceinline__ unsigned short f2bf(float f) {
  unsigned u = __builtin_bit_cast(unsigned, f);
  unsigned r = 0x7FFFu + ((u >> 16) & 1u);
  return (unsigned short)((u + r) >> 16);
}

// ---- kernel 1 (fused fk + inverse DFT, parallel over d):
__global__ __launch_bounds__(512)
void k_h2(const float* __restrict__ w, float* __restrict__ h) {
  __shared__ float red[8];
  const int d = blockIdx.x;
  const int m = threadIdx.x;

  float re = 1.0f, im = 0.0f;
  #pragma unroll
  for (int j = 0; j < FSCOPE; ++j) {
    int t = (m * (j - FSCOPE/2)) % CCH;
    if (t < 0) t += CCH;
    float ang = (2.0f * PI_F / CCH) * (float)t;
    float s, c;
    sincosf(ang, &s, &c);
    float wj = w[j];
    re -= wj * c;
    im += wj * s;
  }

  int t = (m * d) & (CCH - 1);
  float ang = (2.0f * PI_F / CCH) * (float)t;
  float s, c;
  sincosf(ang, &s, &c);
  float inv = 1.0f / (re * re + im * im);
  float term = (c * re + s * im) * inv;

  #pragma unroll
  for (int off = 32; off > 0; off >>= 1)
    term += __shfl_down(term, off, 64);

  const int lane = m & 63, wv = m >> 6;
  if (lane == 0) red[wv] = term;
  __syncthreads();
  if (m == 0) {
    float tot = 0.f;
    #pragma unroll
    for (int i = 0; i < 8; ++i) tot += red[i];
    h[d] = tot / (float)CCH;
  }
}

// ---- kernel 2: H[m][k] = bf16( h[(m-k) mod 512] )
__global__ void k_buildH(const float* __restrict__ h, unsigned short* __restrict__ Hm) {
  int m = blockIdx.x;
  for (int k = threadIdx.x; k < CCH; k += blockDim.x) {
    Hm[m*CCH + k] = f2bf(h[(m - k) & (CCH - 1)]);
  }
}

// ---- kernel 3: Y = H * X
// grid = 4 m-tiles * 392 col-tiles = 1568 blocks, 256 threads (4 waves)
// 32KB LDS, VGPR~68 -> 4 blocks/CU (16 waves/CU)
__global__ __launch_bounds__(256, 4)
void k_gemm(const float* __restrict__ X, const unsigned short* __restrict__ Hm,
            float* __restrict__ Y) {
  __shared__ __align__(16) unsigned char lds[BM*BK*2 + BN*BK*2]; // 16KB A + 16KB B

  const int tid  = threadIdx.x;
  const int lane = tid & 63;
  const int w    = tid >> 6;

  // XCD-aware swizzle (1568 = 8 * 196, exact)
  int bid = blockIdx.x;
  int cpx = gridDim.x >> 3;
  int swz = (bid & 7) * cpx + (bid >> 3);
  const int tm = swz & 3;
  const int tc = swz >> 2;

  const int m0 = tm * BM;
  const int j0 = tc * BN;

  unsigned char* Al = lds;
  unsigned char* Bl = lds + BM*BK*2;

  // B staging mapping: thread -> 4 cols (float4) x 8 k's
  const int fg = tid & 31;
  const int kg = tid >> 5;
  const int jb = j0 + fg*4;
  const int nb = jb / HWSP;
  const int sb = jb - nb * HWSP;
  const float* Xb = X + (size_t)nb * (CCH*(size_t)HWSP) + sb;

  // ---- precomputed LDS offsets (loop-invariant) ----
  // B swizzle: g(col) = (col&7) ^ ((col>>3)&7); slot(col,kq) = kq ^ g(col).
  // Writers (cols 4fg+c, fixed kq=kg) and readers (16 consecutive cols,
  // fixed kq) both spread over all 8 slots -> 2 lanes/slot = free.
  int wrOff[4];
  #pragma unroll
  for (int c = 0; c < 4; ++c) {
    int col = fg*4 + c;
    int g = (col & 7) ^ ((col >> 3) & 7);
    wrOff[c] = col*128 + (((kg ^ g) & 7) << 4);
  }

  const int wr = w >> 1, wc = w & 1;   // wave -> 64x64 quadrant
  int aBase[4], aSw[4], bBase[4], bSw[4];
  #pragma unroll
  for (int fm = 0; fm < 4; ++fm) {
    int m = wr*64 + fm*16 + (lane & 15);
    aBase[fm] = m*128;
    aSw[fm]   = (m & 7) << 4;
  }
  #pragma unroll
  for (int fn = 0; fn < 4; ++fn) {
    int col = wc*64 + fn*16 + (lane & 15);
    bBase[fn] = col*128;
    bSw[fn]   = ((col & 7) ^ ((col >> 3) & 7)) << 4;
  }

  f32x4 acc[4][4];
  #pragma unroll
  for (int i = 0; i < 4; ++i)
    #pragma unroll
    for (int j = 0; j < 4; ++j)
      acc[i][j] = (f32x4){0.f, 0.f, 0.f, 0.f};

  for (int kt = 0; kt < NKT; ++kt) {
    // B global loads (regs only, safe before barrier)
    float4 bv[8];
    const float* Xk = Xb + (size_t)(kt*BK + kg*8) * HWSP;
    #pragma unroll
    for (int kk = 0; kk < 8; ++kk)
      bv[kk] = *reinterpret_cast<const float4*>(Xk + (size_t)kk * HWSP);

    if (kt > 0) __syncthreads();   // previous tile fully consumed

    // A: global_load_lds, pre-swizzled source, linear LDS dest (rule #21)
    #pragma unroll
    for (int i = 0; i < 4; ++i) {
      int m0w = w*32 + i*8;                 // wave-uniform
      int m   = m0w + (lane >> 3);
      int c   = lane & 7;
      const unsigned short* src =
          Hm + (size_t)(m0 + m) * CCH + kt*BK + 8*(c ^ (m & 7));
      unsigned char* dst = Al + m0w * 128;  // + lane*16 by HW
      __builtin_amdgcn_global_load_lds(
          (const __attribute__((address_space(1))) void*)src,
          (__attribute__((address_space(3))) void*)dst, 16, 0, 0);
    }

    // B: cvt fp32->bf16 (v_cvt_pk_bf16_f32 via cast), swizzled ds_write_b128
    #pragma unroll
    for (int c = 0; c < 4; ++c) {
      union { __bf16 h[8]; int4 v; } u;
      #pragma unroll
      for (int kk = 0; kk < 8; ++kk) {
        float f = (c==0) ? bv[kk].x : (c==1) ? bv[kk].y : (c==2) ? bv[kk].z : bv[kk].w;
        u.h[kk] = (__bf16)f;
      }
      *reinterpret_cast<int4*>(Bl + wrOff[c]) = u.v;
    }

    __syncthreads();   // A gload_lds drained + B writes visible

    #pragma unroll
    for (int ks = 0; ks < 2; ++ks) {
      const int kbyte = ks*64 + ((lane >> 4) << 4);
      bf16x8 af[4], bfr[4];
      #pragma unroll
      for (int fm = 0; fm < 4; ++fm)
        af[fm] = *reinterpret_cast<const bf16x8*>(Al + aBase[fm] + (kbyte ^ aSw[fm]));
      #pragma unroll
      for (int fn = 0; fn < 4; ++fn)
        bfr[fn] = *reinterpret_cast<const bf16x8*>(Bl + bBase[fn] + (kbyte ^ bSw[fn]));
      #pragma unroll
      for (int fm = 0; fm < 4; ++fm)
        #pragma unroll
        for (int fn = 0; fn < 4; ++fn)
          acc[fm][fn] = __builtin_amdgcn_mfma_f32_16x16x32_bf16(
              af[fm], bfr[fn], acc[fm][fn], 0, 0, 0);
    }
  }

  // epilogue: C/D layout col = lane&15, row = (lane>>4)*4 + r  (m89/m91)
  #pragma unroll
  for (int fn = 0; fn < 4; ++fn) {
    int colg = j0 + wc*64 + fn*16 + (lane & 15);
    int n = colg / HWSP;
    int s = colg - n * HWSP;
    float* Yb = Y + (size_t)n * (CCH*(size_t)HWSP) + s;
    #pragma unroll
    for (int fm = 0; fm < 4; ++fm) {
      int mrow = m0 + wr*64 + fm*16 + ((lane >> 4) << 2);
      #pragma unroll
      for (int r = 0; r < 4; ++r)
        Yb[(size_t)(mrow + r) * HWSP] = acc[fm][fn][r];
    }
  }
}

extern "C" void kernel_launch(void* const* d_in, const int* in_sizes, int n_in,
                              void* d_out, int out_size, void* d_ws, size_t ws_size,
                              hipStream_t stream) {
  const float* X = (const float*)d_in[0];   // [16,512,56,56] f32
  const float* w = (const float*)d_in[1];   // [27] f32
  float* Y = (float*)d_out;

  float* h           = (float*)d_ws;                                // 2 KB
  unsigned short* Hm = (unsigned short*)((char*)d_ws + 4096);       // 512 KB

  k_h2    <<<CCH, 512, 0, stream>>>(w, h);
  k_buildH<<<CCH, 256, 0, stream>>>(h, Hm);

  const int nblk = (CCH/BM) * (NCOL/BN);    // 4 * 392 = 1568
  k_gemm  <<<nblk, 256, 0, stream>>>(X, Hm, Y);
}